// Round 11
// baseline (326.157 us; speedup 1.0000x reference)
//
#include <hip/hip_runtime.h>

#define EPS 1e-5f

// Problem dims (fixed by setup_inputs)
constexpr int T  = 512;
constexpr int B  = 64;
constexpr int HU = 1024;
constexpr int S  = 1024;
constexpr int C  = B * HU;       // 65536 (b,hu) columns
constexpr int NSLAB = 128;       // one part slab per wave-owned 4-t group

// ws layout (in floats); high-water ~34 MB
constexpr size_t OFF_SIW0 = 0;            // [64][10]
constexpr size_t OFF_W    = 1024;         // [512]    e^{s_tau}, tau<512
constexpr size_t OFF_ESC  = 2048;         // [32768]  e^{s} for ALL (t,b) -> Z
constexpr size_t OFF_W0T  = 34816;        // [10][1024] transposed h-half of W0
constexpr size_t OFF_PART = 45056;        // [128][65536] per-4t-group partials

// ---------------------------------------------------------------------------
// MLP head (10 -> 5 -> 1)
// ---------------------------------------------------------------------------
__device__ __forceinline__ float mlp_head(
    const float* __restrict__ u10,
    const float* __restrict__ b0, const float* __restrict__ g0,
    const float* __restrict__ be0,const float* __restrict__ m0,
    const float* __restrict__ v0,
    const float* __restrict__ W1, const float* __restrict__ b1,
    const float* __restrict__ g1, const float* __restrict__ be1,
    const float* __restrict__ m1, const float* __restrict__ v1,
    const float* __restrict__ W2, const float* __restrict__ b2) {
    float y[10];
#pragma unroll
    for (int j = 0; j < 10; ++j) {
        float u = (u10[j] + b0[j] - m0[j]) * (1.0f / sqrtf(v0[j] + EPS)) * g0[j]
                  + be0[j];
        y[j] = fmaxf(u, 0.f);
    }
    float z[5];
#pragma unroll
    for (int i = 0; i < 5; ++i) {
        float u = b1[i];
#pragma unroll
        for (int j = 0; j < 10; ++j) u = fmaf(y[j], W1[j * 5 + i], u);
        u = (u - m1[i]) * (1.0f / sqrtf(v1[i] + EPS)) * g1[i] + be1[i];
        z[i] = fmaxf(u, 0.f);
    }
    float sc = b2[0];
#pragma unroll
    for (int i = 0; i < 5; ++i) sc = fmaf(z[i], W2[i], sc);
    return sc;
}

// ---------------------------------------------------------------------------
// k_tr: W0T[j][k] = W0[1024+k][j]  (one block). ~1-2 us.
// ---------------------------------------------------------------------------
__global__ __launch_bounds__(1024) void k_tr(const float* __restrict__ W0,
                                             float* __restrict__ W0T) {
    const int k = threadIdx.x;           // 0..1023
    const float* src = W0 + (size_t)(1024 + k) * 10;   // 40B, 8B-aligned
    float v[10];
#pragma unroll
    for (int q = 0; q < 5; ++q) {
        const float2 p = ((const float2*)src)[q];
        v[2 * q] = p.x; v[2 * q + 1] = p.y;
    }
#pragma unroll
    for (int j = 0; j < 10; ++j) W0T[j * 1024 + k] = v[j];
}

// ---------------------------------------------------------------------------
// kA: the 512 USED weights w[tau] = e^{s(t,b)}, tau = t*64+b, t<8.
// Blocks with t==0 also export siW0[b][10]. (Proven r5..r10 — unchanged.)
// ---------------------------------------------------------------------------
__global__ __launch_bounds__(256) void k_weights(
    const float* __restrict__ h,  const float* __restrict__ si,
    const float* __restrict__ W0,
    const float* __restrict__ b0, const float* __restrict__ g0,
    const float* __restrict__ be0,const float* __restrict__ m0,
    const float* __restrict__ v0,
    const float* __restrict__ W1, const float* __restrict__ b1,
    const float* __restrict__ g1, const float* __restrict__ be1,
    const float* __restrict__ m1, const float* __restrict__ v1,
    const float* __restrict__ W2, const float* __restrict__ b2,
    float* __restrict__ w, float* __restrict__ siW0out) {
    const int e   = blockIdx.x;
    const int t   = e >> 6;              // 0..7
    const int cb  = e & 63;              // b
    const int tid = threadIdx.x;
    const int wv  = tid >> 6, ln = tid & 63;

    const float4 hv = *(const float4*)(h  + (size_t)t  * C + (size_t)cb * HU + tid * 4);
    const float4 sv = *(const float4*)(si + (size_t)cb * S + tid * 4);
    const float* wsb = W0 + (size_t)(4 * tid) * 10;          // si half rows
    const float* whb = W0 + (size_t)(1024 + 4 * tid) * 10;   // h half rows

    float ssi[10], shh[10];
#pragma unroll
    for (int j = 0; j < 10; ++j) { ssi[j] = 0.f; shh[j] = 0.f; }
#pragma unroll
    for (int d = 0; d < 4; ++d) {
        const float sx = (&sv.x)[d], hx = (&hv.x)[d];
#pragma unroll
        for (int j = 0; j < 10; ++j) {
            ssi[j] = fmaf(sx, wsb[d * 10 + j], ssi[j]);
            shh[j] = fmaf(hx, whb[d * 10 + j], shh[j]);
        }
    }
#pragma unroll
    for (int j = 0; j < 10; ++j) {
#pragma unroll
        for (int off = 32; off > 0; off >>= 1) {
            ssi[j] += __shfl_down(ssi[j], off, 64);
            shh[j] += __shfl_down(shh[j], off, 64);
        }
    }
    __shared__ float rs[4][10], rh[4][10];
    if (ln == 0) {
#pragma unroll
        for (int j = 0; j < 10; ++j) { rs[wv][j] = ssi[j]; rh[wv][j] = shh[j]; }
    }
    __syncthreads();

    if (t == 0 && tid < 10)
        siW0out[cb * 10 + tid] = rs[0][tid] + rs[1][tid] + rs[2][tid] + rs[3][tid];

    if (tid == 0) {
        float u10[10];
#pragma unroll
        for (int j = 0; j < 10; ++j)
            u10[j] = rs[0][j] + rs[1][j] + rs[2][j] + rs[3][j] +
                     rh[0][j] + rh[1][j] + rh[2][j] + rh[3][j];
        const float sc = mlp_head(u10, b0, g0, be0, m0, v0,
                                  W1, b1, g1, be1, m1, v1, W2, b2);
        w[t * 64 + cb] = expf(sc);   // |sc| BN-bounded -> no max-sub needed
    }
}

// ---------------------------------------------------------------------------
// k_stream v2: BARRIER-FREE single h pass doing BOTH scores and weighted
// sums. Grid 2048 x 256 thr (4 waves). Block (tg,b); wave wv owns 4
// consecutive t's: t0 = 16tg+4wv, one b; slab = 4tg+wv in [0,128).
// Lane ln covers float2 k-slots k2 = 64s+ln (coalesced h AND W0T reads).
// Per strip s (8 strips): 10 w0t float2 (L1/L2-hot, reused x4 rows) +
// 4 h float2; 80 score FMA + 8 wsum FMA — all register-resident.
// Row end: butterfly-reduce sacc, + siW0 -> head -> lane0 writes escore.
// Wave-private part slab (no cross-wave combine). NO LDS, NO barriers,
// NO min-wave VGPR clamp (r10's __launch_bounds__(256,4) forced VGPR=64 ->
// scratch spills, WRITE_SIZE 45MB; this version must show VGPR ~100 and
// WRITE ~34MB).
// ---------------------------------------------------------------------------
__global__ __launch_bounds__(256) void k_stream(
    const float* __restrict__ h,  const float* __restrict__ W0T,
    const float* __restrict__ w,  const float* __restrict__ siW0,
    const float* __restrict__ b0, const float* __restrict__ g0,
    const float* __restrict__ be0,const float* __restrict__ m0,
    const float* __restrict__ v0,
    const float* __restrict__ W1, const float* __restrict__ b1,
    const float* __restrict__ g1, const float* __restrict__ be1,
    const float* __restrict__ m1, const float* __restrict__ v1,
    const float* __restrict__ W2, const float* __restrict__ b2,
    float* __restrict__ escore, float* __restrict__ part) {
    const int b    = blockIdx.x & 63;
    const int tg   = blockIdx.x >> 6;        // 0..31
    const int wv   = threadIdx.x >> 6;       // 0..3
    const int ln   = threadIdx.x & 63;
    const int t0   = tg * 16 + wv * 4;       // wave's 4 t's
    const int slab = tg * 4 + wv;            // 0..127

    const float* hp = h + ((size_t)t0 * 64 + b) * HU;  // row stride 64*HU
    const float wt0 = w[t0 + 0], wt1 = w[t0 + 1];      // uniform -> s_load
    const float wt2 = w[t0 + 2], wt3 = w[t0 + 3];

    float2 acc[8];
#pragma unroll
    for (int s = 0; s < 8; ++s) { acc[s].x = 0.f; acc[s].y = 0.f; }
    float sacc[4][10];
#pragma unroll
    for (int r = 0; r < 4; ++r)
#pragma unroll
        for (int j = 0; j < 10; ++j) sacc[r][j] = 0.f;

#pragma unroll 4
    for (int s = 0; s < 8; ++s) {
        const int k2 = 64 * s + ln;          // float2 slot
        float2 w0t[10];
#pragma unroll
        for (int j = 0; j < 10; ++j)
            w0t[j] = ((const float2*)(W0T + (size_t)j * 1024))[k2];

        const float2 h0 = ((const float2*)hp)[k2];
        const float2 h1 = ((const float2*)(hp + (size_t)1 * 64 * HU))[k2];
        const float2 h2 = ((const float2*)(hp + (size_t)2 * 64 * HU))[k2];
        const float2 h3 = ((const float2*)(hp + (size_t)3 * 64 * HU))[k2];

#pragma unroll
        for (int j = 0; j < 10; ++j) {
            sacc[0][j] = fmaf(h0.x, w0t[j].x, sacc[0][j]);
            sacc[0][j] = fmaf(h0.y, w0t[j].y, sacc[0][j]);
            sacc[1][j] = fmaf(h1.x, w0t[j].x, sacc[1][j]);
            sacc[1][j] = fmaf(h1.y, w0t[j].y, sacc[1][j]);
            sacc[2][j] = fmaf(h2.x, w0t[j].x, sacc[2][j]);
            sacc[2][j] = fmaf(h2.y, w0t[j].y, sacc[2][j]);
            sacc[3][j] = fmaf(h3.x, w0t[j].x, sacc[3][j]);
            sacc[3][j] = fmaf(h3.y, w0t[j].y, sacc[3][j]);
        }
        acc[s].x = fmaf(wt0, h0.x, acc[s].x); acc[s].y = fmaf(wt0, h0.y, acc[s].y);
        acc[s].x = fmaf(wt1, h1.x, acc[s].x); acc[s].y = fmaf(wt1, h1.y, acc[s].y);
        acc[s].x = fmaf(wt2, h2.x, acc[s].x); acc[s].y = fmaf(wt2, h2.y, acc[s].y);
        acc[s].x = fmaf(wt3, h3.x, acc[s].x); acc[s].y = fmaf(wt3, h3.y, acc[s].y);
    }

    // weighted-sum slab first (gets stores in flight under the reduction)
    float* pp = part + (size_t)slab * C + (size_t)b * HU;
#pragma unroll
    for (int s = 0; s < 8; ++s) ((float2*)pp)[64 * s + ln] = acc[s];

    // row epilogues: butterfly reduce (all lanes), head, lane0 stores
#pragma unroll
    for (int r = 0; r < 4; ++r) {
        float u10[10];
#pragma unroll
        for (int j = 0; j < 10; ++j) {
            float v = sacc[r][j];
#pragma unroll
            for (int off = 32; off > 0; off >>= 1)
                v += __shfl_xor(v, off, 64);
            u10[j] = v + siW0[b * 10 + j];
        }
        const float sc = mlp_head(u10, b0, g0, be0, m0, v0,
                                  W1, b1, g1, be1, m1, v1, W2, b2);
        if (ln == 0)
            escore[(size_t)(t0 + r) * 64 + b] = expf(sc);
    }
}

// ---------------------------------------------------------------------------
// kC: Z = sum(escore) (redundant per block, L2-hot), then
// out[c] = (1/Z) * sum_{128 slabs} part[sl][c].  Grid 64 x 256 threads
// (one float4 column per thread; 128 independent slab loads).
// ---------------------------------------------------------------------------
__global__ __launch_bounds__(256) void k_out(const float* __restrict__ part,
                                             const float* __restrict__ escore,
                                             float* __restrict__ out) {
    const int tid = threadIdx.x;
    const int wv  = tid >> 6, ln = tid & 63;

    float zs = 0.f;
#pragma unroll
    for (int q = 0; q < 32; ++q) {
        const float4 v = ((const float4*)escore)[tid + 256 * q];
        zs += v.x + v.y + v.z + v.w;
    }
#pragma unroll
    for (int off = 32; off > 0; off >>= 1)
        zs += __shfl_down(zs, off, 64);
    __shared__ float zr[4];
    __shared__ float sinv;
    if (ln == 0) zr[wv] = zs;
    __syncthreads();
    if (tid == 0) sinv = 1.0f / (zr[0] + zr[1] + zr[2] + zr[3]);
    __syncthreads();
    const float invZ = sinv;

    const int c = blockIdx.x * 1024 + tid * 4;
    float4 s = {0.f, 0.f, 0.f, 0.f};
#pragma unroll 8
    for (int sl = 0; sl < NSLAB; ++sl) {
        const float4 v = *(const float4*)(part + (size_t)sl * C + c);
        s.x += v.x; s.y += v.y; s.z += v.z; s.w += v.w;
    }
    s.x *= invZ; s.y *= invZ; s.z *= invZ; s.w *= invZ;
    *(float4*)(out + c) = s;
}

// ---------------------------------------------------------------------------
extern "C" void kernel_launch(void* const* d_in, const int* in_sizes, int n_in,
                              void* d_out, int out_size, void* d_ws, size_t ws_size,
                              hipStream_t stream) {
    const float* si  = (const float*)d_in[0];
    const float* h   = (const float*)d_in[1];
    const float* W0  = (const float*)d_in[2];
    const float* b0  = (const float*)d_in[3];
    const float* g0  = (const float*)d_in[4];
    const float* be0 = (const float*)d_in[5];
    const float* m0  = (const float*)d_in[6];
    const float* v0  = (const float*)d_in[7];
    const float* W1  = (const float*)d_in[8];
    const float* b1  = (const float*)d_in[9];
    const float* g1  = (const float*)d_in[10];
    const float* be1 = (const float*)d_in[11];
    const float* m1  = (const float*)d_in[12];
    const float* v1  = (const float*)d_in[13];
    const float* W2  = (const float*)d_in[14];
    const float* b2  = (const float*)d_in[15];

    float* ws     = (float*)d_ws;
    float* siW0   = ws + OFF_SIW0;
    float* w      = ws + OFF_W;
    float* escore = ws + OFF_ESC;
    float* W0T    = ws + OFF_W0T;
    float* part   = ws + OFF_PART;
    float* out    = (float*)d_out;

    hipLaunchKernelGGL(k_tr,      dim3(1),    dim3(1024), 0, stream, W0, W0T);
    hipLaunchKernelGGL(k_weights, dim3(512),  dim3(256),  0, stream, h, si, W0,
                       b0, g0, be0, m0, v0, W1, b1, g1, be1, m1, v1, W2, b2,
                       w, siW0);
    hipLaunchKernelGGL(k_stream,  dim3(2048), dim3(256),  0, stream, h, W0T, w,
                       siW0, b0, g0, be0, m0, v0, W1, b1, g1, be1, m1, v1,
                       W2, b2, escore, part);
    hipLaunchKernelGGL(k_out,     dim3(64),   dim3(256),  0, stream, part,
                       escore, out);
}

// Round 12
// 309.639 us; speedup vs baseline: 1.0533x; 1.0533x over previous
//
#include <hip/hip_runtime.h>

#define EPS 1e-5f

// Problem dims (fixed by setup_inputs)
constexpr int T  = 512;
constexpr int B  = 64;
constexpr int HU = 1024;
constexpr int S  = 1024;
constexpr int C  = B * HU;       // 65536 (b,hu) columns
constexpr int NSLAB = 128;       // one part slab per wave-owned 4-t group

// ws layout (in floats); high-water ~34 MB
constexpr size_t OFF_SIW0 = 0;            // [64][10]
constexpr size_t OFF_W    = 1024;         // [512]    e^{s_tau}, tau<512
constexpr size_t OFF_ESC  = 2048;         // [32768]  e^{s} for ALL (t,b) -> Z
constexpr size_t OFF_W0T  = 34816;        // [10][1024] transposed h-half of W0
constexpr size_t OFF_PART = 45056;        // [128][65536] per-4t-group partials

// ---------------------------------------------------------------------------
// MLP head (10 -> 5 -> 1)
// ---------------------------------------------------------------------------
__device__ __forceinline__ float mlp_head(
    const float* __restrict__ u10,
    const float* __restrict__ b0, const float* __restrict__ g0,
    const float* __restrict__ be0,const float* __restrict__ m0,
    const float* __restrict__ v0,
    const float* __restrict__ W1, const float* __restrict__ b1,
    const float* __restrict__ g1, const float* __restrict__ be1,
    const float* __restrict__ m1, const float* __restrict__ v1,
    const float* __restrict__ W2, const float* __restrict__ b2) {
    float y[10];
#pragma unroll
    for (int j = 0; j < 10; ++j) {
        float u = (u10[j] + b0[j] - m0[j]) * (1.0f / sqrtf(v0[j] + EPS)) * g0[j]
                  + be0[j];
        y[j] = fmaxf(u, 0.f);
    }
    float z[5];
#pragma unroll
    for (int i = 0; i < 5; ++i) {
        float u = b1[i];
#pragma unroll
        for (int j = 0; j < 10; ++j) u = fmaf(y[j], W1[j * 5 + i], u);
        u = (u - m1[i]) * (1.0f / sqrtf(v1[i] + EPS)) * g1[i] + be1[i];
        z[i] = fmaxf(u, 0.f);
    }
    float sc = b2[0];
#pragma unroll
    for (int i = 0; i < 5; ++i) sc = fmaf(z[i], W2[i], sc);
    return sc;
}

// ---------------------------------------------------------------------------
// k_tr: W0T[j][k] = W0[1024+k][j]  (one block). ~1-2 us.
// ---------------------------------------------------------------------------
__global__ __launch_bounds__(1024) void k_tr(const float* __restrict__ W0,
                                             float* __restrict__ W0T) {
    const int k = threadIdx.x;           // 0..1023
    const float* src = W0 + (size_t)(1024 + k) * 10;   // 40B, 8B-aligned
    float v[10];
#pragma unroll
    for (int q = 0; q < 5; ++q) {
        const float2 p = ((const float2*)src)[q];
        v[2 * q] = p.x; v[2 * q + 1] = p.y;
    }
#pragma unroll
    for (int j = 0; j < 10; ++j) W0T[j * 1024 + k] = v[j];
}

// ---------------------------------------------------------------------------
// kA: the 512 USED weights w[tau] = e^{s(t,b)}, tau = t*64+b, t<8.
// Blocks with t==0 also export siW0[b][10]. (Proven r5..r11 — unchanged.)
// ---------------------------------------------------------------------------
__global__ __launch_bounds__(256) void k_weights(
    const float* __restrict__ h,  const float* __restrict__ si,
    const float* __restrict__ W0,
    const float* __restrict__ b0, const float* __restrict__ g0,
    const float* __restrict__ be0,const float* __restrict__ m0,
    const float* __restrict__ v0,
    const float* __restrict__ W1, const float* __restrict__ b1,
    const float* __restrict__ g1, const float* __restrict__ be1,
    const float* __restrict__ m1, const float* __restrict__ v1,
    const float* __restrict__ W2, const float* __restrict__ b2,
    float* __restrict__ w, float* __restrict__ siW0out) {
    const int e   = blockIdx.x;
    const int t   = e >> 6;              // 0..7
    const int cb  = e & 63;              // b
    const int tid = threadIdx.x;
    const int wv  = tid >> 6, ln = tid & 63;

    const float4 hv = *(const float4*)(h  + (size_t)t  * C + (size_t)cb * HU + tid * 4);
    const float4 sv = *(const float4*)(si + (size_t)cb * S + tid * 4);
    const float* wsb = W0 + (size_t)(4 * tid) * 10;          // si half rows
    const float* whb = W0 + (size_t)(1024 + 4 * tid) * 10;   // h half rows

    float ssi[10], shh[10];
#pragma unroll
    for (int j = 0; j < 10; ++j) { ssi[j] = 0.f; shh[j] = 0.f; }
#pragma unroll
    for (int d = 0; d < 4; ++d) {
        const float sx = (&sv.x)[d], hx = (&hv.x)[d];
#pragma unroll
        for (int j = 0; j < 10; ++j) {
            ssi[j] = fmaf(sx, wsb[d * 10 + j], ssi[j]);
            shh[j] = fmaf(hx, whb[d * 10 + j], shh[j]);
        }
    }
#pragma unroll
    for (int j = 0; j < 10; ++j) {
#pragma unroll
        for (int off = 32; off > 0; off >>= 1) {
            ssi[j] += __shfl_down(ssi[j], off, 64);
            shh[j] += __shfl_down(shh[j], off, 64);
        }
    }
    __shared__ float rs[4][10], rh[4][10];
    if (ln == 0) {
#pragma unroll
        for (int j = 0; j < 10; ++j) { rs[wv][j] = ssi[j]; rh[wv][j] = shh[j]; }
    }
    __syncthreads();

    if (t == 0 && tid < 10)
        siW0out[cb * 10 + tid] = rs[0][tid] + rs[1][tid] + rs[2][tid] + rs[3][tid];

    if (tid == 0) {
        float u10[10];
#pragma unroll
        for (int j = 0; j < 10; ++j)
            u10[j] = rs[0][j] + rs[1][j] + rs[2][j] + rs[3][j] +
                     rh[0][j] + rh[1][j] + rh[2][j] + rh[3][j];
        const float sc = mlp_head(u10, b0, g0, be0, m0, v0,
                                  W1, b1, g1, be1, m1, v1, W2, b2);
        w[t * 64 + cb] = expf(sc);   // |sc| BN-bounded -> no max-sub needed
    }
}

// ---------------------------------------------------------------------------
// k_stream v3: identical to v2 EXCEPT __launch_bounds__(256, 2).
// Register post-mortem across rounds:
//   r10: __launch_bounds__(256,4) -> VGPR=64  -> scratch spills (WRITE 45MB)
//   r11: no bounds -> compiler chose VGPR=68  -> LDS spills (LDS 16KB,
//        2.36M bank conflicts) — occupancy heuristic strikes again.
// Live state needs ~100 VGPR (sacc 40 + acc 16 + w0t 20 + h 8 + addr).
// (256,2) sets the allocator budget to <=256 VGPR -> ~100-120 alloc, ZERO
// spills, real occupancy 4-5 waves/SIMD from the 2048-block grid.
// Verification targets: VGPR>=96, LDS_Block_Size=0, BANK_CONFLICT~0.
// ---------------------------------------------------------------------------
__global__ __launch_bounds__(256, 2) void k_stream(
    const float* __restrict__ h,  const float* __restrict__ W0T,
    const float* __restrict__ w,  const float* __restrict__ siW0,
    const float* __restrict__ b0, const float* __restrict__ g0,
    const float* __restrict__ be0,const float* __restrict__ m0,
    const float* __restrict__ v0,
    const float* __restrict__ W1, const float* __restrict__ b1,
    const float* __restrict__ g1, const float* __restrict__ be1,
    const float* __restrict__ m1, const float* __restrict__ v1,
    const float* __restrict__ W2, const float* __restrict__ b2,
    float* __restrict__ escore, float* __restrict__ part) {
    const int b    = blockIdx.x & 63;
    const int tg   = blockIdx.x >> 6;        // 0..31
    const int wv   = threadIdx.x >> 6;       // 0..3
    const int ln   = threadIdx.x & 63;
    const int t0   = tg * 16 + wv * 4;       // wave's 4 t's
    const int slab = tg * 4 + wv;            // 0..127

    const float* hp = h + ((size_t)t0 * 64 + b) * HU;  // row stride 64*HU
    const float wt0 = w[t0 + 0], wt1 = w[t0 + 1];      // uniform -> s_load
    const float wt2 = w[t0 + 2], wt3 = w[t0 + 3];

    float2 acc[8];
#pragma unroll
    for (int s = 0; s < 8; ++s) { acc[s].x = 0.f; acc[s].y = 0.f; }
    float sacc[4][10];
#pragma unroll
    for (int r = 0; r < 4; ++r)
#pragma unroll
        for (int j = 0; j < 10; ++j) sacc[r][j] = 0.f;

#pragma unroll 4
    for (int s = 0; s < 8; ++s) {
        const int k2 = 64 * s + ln;          // float2 slot
        float2 w0t[10];
#pragma unroll
        for (int j = 0; j < 10; ++j)
            w0t[j] = ((const float2*)(W0T + (size_t)j * 1024))[k2];

        const float2 h0 = ((const float2*)hp)[k2];
        const float2 h1 = ((const float2*)(hp + (size_t)1 * 64 * HU))[k2];
        const float2 h2 = ((const float2*)(hp + (size_t)2 * 64 * HU))[k2];
        const float2 h3 = ((const float2*)(hp + (size_t)3 * 64 * HU))[k2];

#pragma unroll
        for (int j = 0; j < 10; ++j) {
            sacc[0][j] = fmaf(h0.x, w0t[j].x, sacc[0][j]);
            sacc[0][j] = fmaf(h0.y, w0t[j].y, sacc[0][j]);
            sacc[1][j] = fmaf(h1.x, w0t[j].x, sacc[1][j]);
            sacc[1][j] = fmaf(h1.y, w0t[j].y, sacc[1][j]);
            sacc[2][j] = fmaf(h2.x, w0t[j].x, sacc[2][j]);
            sacc[2][j] = fmaf(h2.y, w0t[j].y, sacc[2][j]);
            sacc[3][j] = fmaf(h3.x, w0t[j].x, sacc[3][j]);
            sacc[3][j] = fmaf(h3.y, w0t[j].y, sacc[3][j]);
        }
        acc[s].x = fmaf(wt0, h0.x, acc[s].x); acc[s].y = fmaf(wt0, h0.y, acc[s].y);
        acc[s].x = fmaf(wt1, h1.x, acc[s].x); acc[s].y = fmaf(wt1, h1.y, acc[s].y);
        acc[s].x = fmaf(wt2, h2.x, acc[s].x); acc[s].y = fmaf(wt2, h2.y, acc[s].y);
        acc[s].x = fmaf(wt3, h3.x, acc[s].x); acc[s].y = fmaf(wt3, h3.y, acc[s].y);
    }

    // weighted-sum slab first (gets stores in flight under the reduction)
    float* pp = part + (size_t)slab * C + (size_t)b * HU;
#pragma unroll
    for (int s = 0; s < 8; ++s) ((float2*)pp)[64 * s + ln] = acc[s];

    // row epilogues: butterfly reduce (all lanes), head, lane0 stores
#pragma unroll
    for (int r = 0; r < 4; ++r) {
        float u10[10];
#pragma unroll
        for (int j = 0; j < 10; ++j) {
            float v = sacc[r][j];
#pragma unroll
            for (int off = 32; off > 0; off >>= 1)
                v += __shfl_xor(v, off, 64);
            u10[j] = v + siW0[b * 10 + j];
        }
        const float sc = mlp_head(u10, b0, g0, be0, m0, v0,
                                  W1, b1, g1, be1, m1, v1, W2, b2);
        if (ln == 0)
            escore[(size_t)(t0 + r) * 64 + b] = expf(sc);
    }
}

// ---------------------------------------------------------------------------
// kC: Z = sum(escore) (redundant per block, L2-hot), then
// out[c] = (1/Z) * sum_{128 slabs} part[sl][c].  Grid 64 x 256 threads.
// ---------------------------------------------------------------------------
__global__ __launch_bounds__(256) void k_out(const float* __restrict__ part,
                                             const float* __restrict__ escore,
                                             float* __restrict__ out) {
    const int tid = threadIdx.x;
    const int wv  = tid >> 6, ln = tid & 63;

    float zs = 0.f;
#pragma unroll
    for (int q = 0; q < 32; ++q) {
        const float4 v = ((const float4*)escore)[tid + 256 * q];
        zs += v.x + v.y + v.z + v.w;
    }
#pragma unroll
    for (int off = 32; off > 0; off >>= 1)
        zs += __shfl_down(zs, off, 64);
    __shared__ float zr[4];
    __shared__ float sinv;
    if (ln == 0) zr[wv] = zs;
    __syncthreads();
    if (tid == 0) sinv = 1.0f / (zr[0] + zr[1] + zr[2] + zr[3]);
    __syncthreads();
    const float invZ = sinv;

    const int c = blockIdx.x * 1024 + tid * 4;
    float4 s = {0.f, 0.f, 0.f, 0.f};
#pragma unroll 8
    for (int sl = 0; sl < NSLAB; ++sl) {
        const float4 v = *(const float4*)(part + (size_t)sl * C + c);
        s.x += v.x; s.y += v.y; s.z += v.z; s.w += v.w;
    }
    s.x *= invZ; s.y *= invZ; s.z *= invZ; s.w *= invZ;
    *(float4*)(out + c) = s;
}

// ---------------------------------------------------------------------------
extern "C" void kernel_launch(void* const* d_in, const int* in_sizes, int n_in,
                              void* d_out, int out_size, void* d_ws, size_t ws_size,
                              hipStream_t stream) {
    const float* si  = (const float*)d_in[0];
    const float* h   = (const float*)d_in[1];
    const float* W0  = (const float*)d_in[2];
    const float* b0  = (const float*)d_in[3];
    const float* g0  = (const float*)d_in[4];
    const float* be0 = (const float*)d_in[5];
    const float* m0  = (const float*)d_in[6];
    const float* v0  = (const float*)d_in[7];
    const float* W1  = (const float*)d_in[8];
    const float* b1  = (const float*)d_in[9];
    const float* g1  = (const float*)d_in[10];
    const float* be1 = (const float*)d_in[11];
    const float* m1  = (const float*)d_in[12];
    const float* v1  = (const float*)d_in[13];
    const float* W2  = (const float*)d_in[14];
    const float* b2  = (const float*)d_in[15];

    float* ws     = (float*)d_ws;
    float* siW0   = ws + OFF_SIW0;
    float* w      = ws + OFF_W;
    float* escore = ws + OFF_ESC;
    float* W0T    = ws + OFF_W0T;
    float* part   = ws + OFF_PART;
    float* out    = (float*)d_out;

    hipLaunchKernelGGL(k_tr,      dim3(1),    dim3(1024), 0, stream, W0, W0T);
    hipLaunchKernelGGL(k_weights, dim3(512),  dim3(256),  0, stream, h, si, W0,
                       b0, g0, be0, m0, v0, W1, b1, g1, be1, m1, v1, W2, b2,
                       w, siW0);
    hipLaunchKernelGGL(k_stream,  dim3(2048), dim3(256),  0, stream, h, W0T, w,
                       siW0, b0, g0, be0, m0, v0, W1, b1, g1, be1, m1, v1,
                       W2, b2, escore, part);
    hipLaunchKernelGGL(k_out,     dim3(64),   dim3(256),  0, stream, part,
                       escore, out);
}

// Round 13
// 290.385 us; speedup vs baseline: 1.1232x; 1.0663x over previous
//
#include <hip/hip_runtime.h>

#define EPS 1e-5f

// Problem dims (fixed by setup_inputs)
constexpr int T  = 512;
constexpr int B  = 64;
constexpr int HU = 1024;
constexpr int S  = 1024;
constexpr int C  = B * HU;       // 65536 (b,hu) columns
constexpr int NSLAB = 128;       // one part slab per wave-owned 4-t group

// ws layout (in floats); high-water ~34 MB
constexpr size_t OFF_SIW0 = 0;            // [64][10]
constexpr size_t OFF_W    = 1024;         // [512]    e^{s_tau}, tau<512
constexpr size_t OFF_ESC  = 2048;         // [32768]  e^{s} for ALL (t,b) -> Z
constexpr size_t OFF_W0T  = 34816;        // [10][1024] transposed h-half of W0
constexpr size_t OFF_PART = 45056;        // [128][65536] per-4t-group partials

// ---------------------------------------------------------------------------
// MLP head (10 -> 5 -> 1)
// ---------------------------------------------------------------------------
__device__ __forceinline__ float mlp_head(
    const float* __restrict__ u10,
    const float* __restrict__ b0, const float* __restrict__ g0,
    const float* __restrict__ be0,const float* __restrict__ m0,
    const float* __restrict__ v0,
    const float* __restrict__ W1, const float* __restrict__ b1,
    const float* __restrict__ g1, const float* __restrict__ be1,
    const float* __restrict__ m1, const float* __restrict__ v1,
    const float* __restrict__ W2, const float* __restrict__ b2) {
    float y[10];
#pragma unroll
    for (int j = 0; j < 10; ++j) {
        float u = (u10[j] + b0[j] - m0[j]) * (1.0f / sqrtf(v0[j] + EPS)) * g0[j]
                  + be0[j];
        y[j] = fmaxf(u, 0.f);
    }
    float z[5];
#pragma unroll
    for (int i = 0; i < 5; ++i) {
        float u = b1[i];
#pragma unroll
        for (int j = 0; j < 10; ++j) u = fmaf(y[j], W1[j * 5 + i], u);
        u = (u - m1[i]) * (1.0f / sqrtf(v1[i] + EPS)) * g1[i] + be1[i];
        z[i] = fmaxf(u, 0.f);
    }
    float sc = b2[0];
#pragma unroll
    for (int i = 0; i < 5; ++i) sc = fmaf(z[i], W2[i], sc);
    return sc;
}

// ---------------------------------------------------------------------------
// k_tr: W0T[j][k] = W0[1024+k][j]  (one block). ~1-2 us.
// ---------------------------------------------------------------------------
__global__ __launch_bounds__(1024) void k_tr(const float* __restrict__ W0,
                                             float* __restrict__ W0T) {
    const int k = threadIdx.x;           // 0..1023
    const float* src = W0 + (size_t)(1024 + k) * 10;   // 40B, 8B-aligned
    float v[10];
#pragma unroll
    for (int q = 0; q < 5; ++q) {
        const float2 p = ((const float2*)src)[q];
        v[2 * q] = p.x; v[2 * q + 1] = p.y;
    }
#pragma unroll
    for (int j = 0; j < 10; ++j) W0T[j * 1024 + k] = v[j];
}

// ---------------------------------------------------------------------------
// kA: the 512 USED weights w[tau] = e^{s(t,b)}, tau = t*64+b, t<8.
// Blocks with t==0 also export siW0[b][10]. (Proven r5..r12 — unchanged.)
// ---------------------------------------------------------------------------
__global__ __launch_bounds__(256) void k_weights(
    const float* __restrict__ h,  const float* __restrict__ si,
    const float* __restrict__ W0,
    const float* __restrict__ b0, const float* __restrict__ g0,
    const float* __restrict__ be0,const float* __restrict__ m0,
    const float* __restrict__ v0,
    const float* __restrict__ W1, const float* __restrict__ b1,
    const float* __restrict__ g1, const float* __restrict__ be1,
    const float* __restrict__ m1, const float* __restrict__ v1,
    const float* __restrict__ W2, const float* __restrict__ b2,
    float* __restrict__ w, float* __restrict__ siW0out) {
    const int e   = blockIdx.x;
    const int t   = e >> 6;              // 0..7
    const int cb  = e & 63;              // b
    const int tid = threadIdx.x;
    const int wv  = tid >> 6, ln = tid & 63;

    const float4 hv = *(const float4*)(h  + (size_t)t  * C + (size_t)cb * HU + tid * 4);
    const float4 sv = *(const float4*)(si + (size_t)cb * S + tid * 4);
    const float* wsb = W0 + (size_t)(4 * tid) * 10;          // si half rows
    const float* whb = W0 + (size_t)(1024 + 4 * tid) * 10;   // h half rows

    float ssi[10], shh[10];
#pragma unroll
    for (int j = 0; j < 10; ++j) { ssi[j] = 0.f; shh[j] = 0.f; }
#pragma unroll
    for (int d = 0; d < 4; ++d) {
        const float sx = (&sv.x)[d], hx = (&hv.x)[d];
#pragma unroll
        for (int j = 0; j < 10; ++j) {
            ssi[j] = fmaf(sx, wsb[d * 10 + j], ssi[j]);
            shh[j] = fmaf(hx, whb[d * 10 + j], shh[j]);
        }
    }
#pragma unroll
    for (int j = 0; j < 10; ++j) {
#pragma unroll
        for (int off = 32; off > 0; off >>= 1) {
            ssi[j] += __shfl_down(ssi[j], off, 64);
            shh[j] += __shfl_down(shh[j], off, 64);
        }
    }
    __shared__ float rs[4][10], rh[4][10];
    if (ln == 0) {
#pragma unroll
        for (int j = 0; j < 10; ++j) { rs[wv][j] = ssi[j]; rh[wv][j] = shh[j]; }
    }
    __syncthreads();

    if (t == 0 && tid < 10)
        siW0out[cb * 10 + tid] = rs[0][tid] + rs[1][tid] + rs[2][tid] + rs[3][tid];

    if (tid == 0) {
        float u10[10];
#pragma unroll
        for (int j = 0; j < 10; ++j)
            u10[j] = rs[0][j] + rs[1][j] + rs[2][j] + rs[3][j] +
                     rh[0][j] + rh[1][j] + rh[2][j] + rh[3][j];
        const float sc = mlp_head(u10, b0, g0, be0, m0, v0,
                                  W1, b1, g1, be1, m1, v1, W2, b2);
        w[t * 64 + cb] = expf(sc);   // |sc| BN-bounded -> no max-sub needed
    }
}

// ---------------------------------------------------------------------------
// k_stream v4: the r11/r12 phantom-LDS bug is FIXED.
// Root cause (rule #20): `float2 acc[8]` under `#pragma unroll 4` left the
// strip index runtime -> PromoteAlloca moved the array to LDS (exactly
// 256thr x 16f = 16384B), stride-64B per thread -> 2.36M bank conflicts.
// PromoteAlloca runs before RA, so no __launch_bounds__ could undo it
// (r10 scratch spills / r11-r12 LDS were the same bug).
// Fix: acc[s] lives only within strip s -> replaced by a strip-local
// float2, stored to part at strip end; strip loop FULLY unrolled so every
// index is compile-time. Verification: LDS_Block_Size MUST be 0,
// BANK_CONFLICT ~0, VGPR ~90-120.
// ---------------------------------------------------------------------------
__global__ __launch_bounds__(256, 2) void k_stream(
    const float* __restrict__ h,  const float* __restrict__ W0T,
    const float* __restrict__ w,  const float* __restrict__ siW0,
    const float* __restrict__ b0, const float* __restrict__ g0,
    const float* __restrict__ be0,const float* __restrict__ m0,
    const float* __restrict__ v0,
    const float* __restrict__ W1, const float* __restrict__ b1,
    const float* __restrict__ g1, const float* __restrict__ be1,
    const float* __restrict__ m1, const float* __restrict__ v1,
    const float* __restrict__ W2, const float* __restrict__ b2,
    float* __restrict__ escore, float* __restrict__ part) {
    const int b    = blockIdx.x & 63;
    const int tg   = blockIdx.x >> 6;        // 0..31
    const int wv   = threadIdx.x >> 6;       // 0..3
    const int ln   = threadIdx.x & 63;
    const int t0   = tg * 16 + wv * 4;       // wave's 4 t's
    const int slab = tg * 4 + wv;            // 0..127

    const float* hp = h + ((size_t)t0 * 64 + b) * HU;  // row stride 64*HU
    float* pp = part + (size_t)slab * C + (size_t)b * HU;
    const float wt0 = w[t0 + 0], wt1 = w[t0 + 1];      // uniform -> s_load
    const float wt2 = w[t0 + 2], wt3 = w[t0 + 3];

    float sacc[4][10];
#pragma unroll
    for (int r = 0; r < 4; ++r)
#pragma unroll
        for (int j = 0; j < 10; ++j) sacc[r][j] = 0.f;

#pragma unroll
    for (int s = 0; s < 8; ++s) {
        const int k2 = 64 * s + ln;          // float2 slot (compile-time s)
        float2 w0t[10];
#pragma unroll
        for (int j = 0; j < 10; ++j)
            w0t[j] = ((const float2*)(W0T + (size_t)j * 1024))[k2];

        const float2 h0 = ((const float2*)hp)[k2];
        const float2 h1 = ((const float2*)(hp + (size_t)1 * 64 * HU))[k2];
        const float2 h2 = ((const float2*)(hp + (size_t)2 * 64 * HU))[k2];
        const float2 h3 = ((const float2*)(hp + (size_t)3 * 64 * HU))[k2];

#pragma unroll
        for (int j = 0; j < 10; ++j) {
            sacc[0][j] = fmaf(h0.x, w0t[j].x, sacc[0][j]);
            sacc[0][j] = fmaf(h0.y, w0t[j].y, sacc[0][j]);
            sacc[1][j] = fmaf(h1.x, w0t[j].x, sacc[1][j]);
            sacc[1][j] = fmaf(h1.y, w0t[j].y, sacc[1][j]);
            sacc[2][j] = fmaf(h2.x, w0t[j].x, sacc[2][j]);
            sacc[2][j] = fmaf(h2.y, w0t[j].y, sacc[2][j]);
            sacc[3][j] = fmaf(h3.x, w0t[j].x, sacc[3][j]);
            sacc[3][j] = fmaf(h3.y, w0t[j].y, sacc[3][j]);
        }

        // strip-local weighted sum -> stored immediately (no acc[] array)
        float2 a;
        a.x = wt0 * h0.x; a.y = wt0 * h0.y;
        a.x = fmaf(wt1, h1.x, a.x); a.y = fmaf(wt1, h1.y, a.y);
        a.x = fmaf(wt2, h2.x, a.x); a.y = fmaf(wt2, h2.y, a.y);
        a.x = fmaf(wt3, h3.x, a.x); a.y = fmaf(wt3, h3.y, a.y);
        ((float2*)pp)[k2] = a;
    }

    // row epilogues: butterfly reduce (all lanes), head, lane0 stores
#pragma unroll
    for (int r = 0; r < 4; ++r) {
        float u10[10];
#pragma unroll
        for (int j = 0; j < 10; ++j) {
            float v = sacc[r][j];
#pragma unroll
            for (int off = 32; off > 0; off >>= 1)
                v += __shfl_xor(v, off, 64);
            u10[j] = v + siW0[b * 10 + j];
        }
        const float sc = mlp_head(u10, b0, g0, be0, m0, v0,
                                  W1, b1, g1, be1, m1, v1, W2, b2);
        if (ln == 0)
            escore[(size_t)(t0 + r) * 64 + b] = expf(sc);
    }
}

// ---------------------------------------------------------------------------
// kC: Z = sum(escore) (redundant per block, L2-hot), then
// out[c] = (1/Z) * sum_{128 slabs} part[sl][c].  Grid 64 x 256 threads.
// ---------------------------------------------------------------------------
__global__ __launch_bounds__(256) void k_out(const float* __restrict__ part,
                                             const float* __restrict__ escore,
                                             float* __restrict__ out) {
    const int tid = threadIdx.x;
    const int wv  = tid >> 6, ln = tid & 63;

    float zs = 0.f;
#pragma unroll
    for (int q = 0; q < 32; ++q) {
        const float4 v = ((const float4*)escore)[tid + 256 * q];
        zs += v.x + v.y + v.z + v.w;
    }
#pragma unroll
    for (int off = 32; off > 0; off >>= 1)
        zs += __shfl_down(zs, off, 64);
    __shared__ float zr[4];
    __shared__ float sinv;
    if (ln == 0) zr[wv] = zs;
    __syncthreads();
    if (tid == 0) sinv = 1.0f / (zr[0] + zr[1] + zr[2] + zr[3]);
    __syncthreads();
    const float invZ = sinv;

    const int c = blockIdx.x * 1024 + tid * 4;
    float4 s = {0.f, 0.f, 0.f, 0.f};
#pragma unroll 8
    for (int sl = 0; sl < NSLAB; ++sl) {
        const float4 v = *(const float4*)(part + (size_t)sl * C + c);
        s.x += v.x; s.y += v.y; s.z += v.z; s.w += v.w;
    }
    s.x *= invZ; s.y *= invZ; s.z *= invZ; s.w *= invZ;
    *(float4*)(out + c) = s;
}

// ---------------------------------------------------------------------------
extern "C" void kernel_launch(void* const* d_in, const int* in_sizes, int n_in,
                              void* d_out, int out_size, void* d_ws, size_t ws_size,
                              hipStream_t stream) {
    const float* si  = (const float*)d_in[0];
    const float* h   = (const float*)d_in[1];
    const float* W0  = (const float*)d_in[2];
    const float* b0  = (const float*)d_in[3];
    const float* g0  = (const float*)d_in[4];
    const float* be0 = (const float*)d_in[5];
    const float* m0  = (const float*)d_in[6];
    const float* v0  = (const float*)d_in[7];
    const float* W1  = (const float*)d_in[8];
    const float* b1  = (const float*)d_in[9];
    const float* g1  = (const float*)d_in[10];
    const float* be1 = (const float*)d_in[11];
    const float* m1  = (const float*)d_in[12];
    const float* v1  = (const float*)d_in[13];
    const float* W2  = (const float*)d_in[14];
    const float* b2  = (const float*)d_in[15];

    float* ws     = (float*)d_ws;
    float* siW0   = ws + OFF_SIW0;
    float* w      = ws + OFF_W;
    float* escore = ws + OFF_ESC;
    float* W0T    = ws + OFF_W0T;
    float* part   = ws + OFF_PART;
    float* out    = (float*)d_out;

    hipLaunchKernelGGL(k_tr,      dim3(1),    dim3(1024), 0, stream, W0, W0T);
    hipLaunchKernelGGL(k_weights, dim3(512),  dim3(256),  0, stream, h, si, W0,
                       b0, g0, be0, m0, v0, W1, b1, g1, be1, m1, v1, W2, b2,
                       w, siW0);
    hipLaunchKernelGGL(k_stream,  dim3(2048), dim3(256),  0, stream, h, W0T, w,
                       siW0, b0, g0, be0, m0, v0, W1, b1, g1, be1, m1, v1,
                       W2, b2, escore, part);
    hipLaunchKernelGGL(k_out,     dim3(64),   dim3(256),  0, stream, part,
                       escore, out);
}